// Round 1
// baseline (1039.518 us; speedup 1.0000x reference)
//
#include <hip/hip_runtime.h>
#include <hip/hip_bf16.h>
#include <math.h>

#define D 256
#define H 8
#define C 32
#define DE 64
#define DF 1024

static inline size_t align_up(size_t x, size_t a) { return (x + a - 1) / a * a; }

// ---------------- CSR build ----------------
__global__ void deg_kernel(const int* __restrict__ dst, int* __restrict__ deg, int E) {
    int e = blockIdx.x * 256 + threadIdx.x;
    if (e < E) atomicAdd(&deg[dst[e]], 1);
}

__global__ void scan_kernel(const int* __restrict__ deg, int* __restrict__ off, int n) {
    __shared__ int buf[1024];
    __shared__ int carryS;
    int tid = threadIdx.x;
    if (tid == 0) carryS = 0;
    __syncthreads();
    for (int base = 0; base < n; base += 1024) {
        int i = base + tid;
        int v = (i < n) ? deg[i] : 0;
        buf[tid] = v;
        __syncthreads();
        for (int s = 1; s < 1024; s <<= 1) {
            int tmp = (tid >= s) ? buf[tid - s] : 0;
            __syncthreads();
            if (tid >= s) buf[tid] += tmp;
            __syncthreads();
        }
        if (i < n) off[i] = carryS + buf[tid] - v;  // exclusive
        __syncthreads();
        if (tid == 0) carryS += buf[1023];
        __syncthreads();
    }
    if (tid == 0) off[n] = carryS;
}

__global__ void copy_int_kernel(const int* __restrict__ a, int* __restrict__ b, int n) {
    int i = blockIdx.x * 256 + threadIdx.x;
    if (i < n) b[i] = a[i];
}

__global__ void fill_kernel(const int* __restrict__ dst, int* __restrict__ cursor,
                            int* __restrict__ eid, int E) {
    int e = blockIdx.x * 256 + threadIdx.x;
    if (e < E) {
        int p = atomicAdd(&cursor[dst[e]], 1);
        eid[p] = e;
    }
}

// ---------------- edge-attention projection ----------------
// Me[d,h] = sum_c We[d, h*C+c] * ae[h,c]   (collapses (ea@We * a_e).sum(-1) to ea@Me)
__global__ void me_kernel(const float* __restrict__ We, const float* __restrict__ ae,
                          float* __restrict__ Me) {
    int t = threadIdx.x;  // 512 threads
    int d = t >> 3, h = t & 7;
    float s = 0.f;
    for (int c = 0; c < C; ++c) s += We[d * (H * C) + h * C + c] * ae[h * C + c];
    Me[d * H + h] = s;
}

// eA{1,2}[e,h] = ew[e,:] @ Me{1,2}[:,h]; also segment-sum into sA by dst (for self-loop attr)
__global__ void ealpha_kernel(const float* __restrict__ ew, const int* __restrict__ dst,
                              const float* __restrict__ Me1, const float* __restrict__ Me2,
                              float* __restrict__ eA1, float* __restrict__ eA2,
                              float* __restrict__ sA1, float* __restrict__ sA2, int E) {
    __shared__ float M1[DE * H], M2[DE * H];
    int t = threadIdx.x;
    for (int i = t; i < DE * H; i += 256) { M1[i] = Me1[i]; M2[i] = Me2[i]; }
    __syncthreads();
    long long idx = (long long)blockIdx.x * 256 + t;
    int e = (int)(idx >> 3), hh = (int)(idx & 7);
    if (e < E) {
        const float* row = ew + (size_t)e * DE;
        float a1 = 0.f, a2 = 0.f;
        for (int d = 0; d < DE; ++d) {
            float v = row[d];
            a1 += v * M1[d * H + hh];
            a2 += v * M2[d * H + hh];
        }
        eA1[(size_t)e * H + hh] = a1;
        eA2[(size_t)e * H + hh] = a2;
        int dn = dst[e];
        atomicAdd(&sA1[dn * H + hh], a1);
        atomicAdd(&sA2[dn * H + hh], a2);
    }
}

// asrc[n,h] = sum_c xs[n,h,c]*a_s[h,c]; adst likewise
__global__ void attnparam_kernel(const float* __restrict__ xs, const float* __restrict__ a_s,
                                 const float* __restrict__ a_d, float* __restrict__ asrc,
                                 float* __restrict__ adst, int N) {
    __shared__ float AS[D], AD[D];
    int t = threadIdx.x;
    AS[t] = a_s[t]; AD[t] = a_d[t];
    __syncthreads();
    int idx = blockIdx.x * 256 + t;
    int n = idx >> 3, hh = idx & 7;
    if (n < N) {
        const float* row = xs + (size_t)n * D + hh * C;
        float s1 = 0.f, s2 = 0.f;
        for (int c = 0; c < C; ++c) {
            float v = row[c];
            s1 += v * AS[hh * C + c];
            s2 += v * AD[hh * C + c];
        }
        asrc[idx] = s1; adst[idx] = s2;
    }
}

// ---------------- generic fp32 tiled GEMM: C = A[MxK] @ B[KxN] (+bias)(+relu) ----------------
__global__ __launch_bounds__(256) void gemm_kernel(const float* __restrict__ A,
                                                   const float* __restrict__ B,
                                                   const float* __restrict__ bias,
                                                   float* __restrict__ Cc,
                                                   int M, int Nc, int K, int relu) {
    __shared__ float As[16][64 + 1];  // [k][m]
    __shared__ float Bs[16][64 + 1];  // [k][n]
    int t = threadIdx.x;
    int tx = t & 15, ty = t >> 4;
    int bm = blockIdx.x * 64, bn = blockIdx.y * 64;
    float acc[4][4] = {};
    for (int k0 = 0; k0 < K; k0 += 16) {
#pragma unroll
        for (int i = 0; i < 4; ++i) {
            int l = t + 256 * i;
            int r = l >> 4, c = l & 15;
            int gr = bm + r;
            As[c][r] = (gr < M) ? A[(size_t)gr * K + k0 + c] : 0.f;
        }
#pragma unroll
        for (int i = 0; i < 4; ++i) {
            int l = t + 256 * i;
            int r = l >> 6, c = l & 63;
            Bs[r][c] = B[(size_t)(k0 + r) * Nc + bn + c];
        }
        __syncthreads();
#pragma unroll
        for (int k = 0; k < 16; ++k) {
            float a[4], b[4];
#pragma unroll
            for (int i = 0; i < 4; ++i) a[i] = As[k][ty * 4 + i];
#pragma unroll
            for (int j = 0; j < 4; ++j) b[j] = Bs[k][tx * 4 + j];
#pragma unroll
            for (int i = 0; i < 4; ++i)
#pragma unroll
                for (int j = 0; j < 4; ++j) acc[i][j] = fmaf(a[i], b[j], acc[i][j]);
        }
        __syncthreads();
    }
#pragma unroll
    for (int i = 0; i < 4; ++i) {
        int gr = bm + ty * 4 + i;
        if (gr >= M) continue;
#pragma unroll
        for (int j = 0; j < 4; ++j) {
            int gc = bn + tx * 4 + j;
            float v = acc[i][j];
            if (bias) v += bias[gc];
            if (relu) v = fmaxf(v, 0.f);
            Cc[(size_t)gr * Nc + gc] = v;
        }
    }
}

// ---------------- GAT per-node aggregation + fused LN/leaky/residual ----------------
// One block (256 threads) per node. t = feature index (h = t/32, c = t%32).
// Softmax computed without max-subtraction (alpha is O(1); shift-invariant).
__global__ __launch_bounds__(256) void gat_node_kernel(
    const int* __restrict__ off, const int* __restrict__ eid, const int* __restrict__ src,
    const float* __restrict__ eA, const float* __restrict__ sA,
    const float* __restrict__ asrc, const float* __restrict__ adst,
    const float* __restrict__ xs, const float* __restrict__ nf_in,
    const float* __restrict__ bias, const float* __restrict__ gamma,
    const float* __restrict__ beta, float* __restrict__ nf_out) {
    int n = blockIdx.x;
    int t = threadIdx.x;
    int h = t >> 5;
    __shared__ float exS[8][8];   // [edge-slot][head]
    __shared__ int srcS[8];
    __shared__ float exSelfS[8];
    __shared__ float denS[8];
    __shared__ float r1[4], r2[4];

    int e0 = off[n], e1 = off[n + 1];
    int degn = e1 - e0;

    if (t < 8) {
        float sa = sA[n * 8 + t] / (float)(degn > 0 ? degn : 1);  // loop_attr @ Me
        float al = asrc[n * 8 + t] + adst[n * 8 + t] + sa;
        al = al > 0.f ? al : 0.2f * al;
        exSelfS[t] = expf(al);
    }
    __syncthreads();

    int hh = t & 7;
    float adst_n = 0.f, denAcc = 0.f;
    if (t < 64) {
        adst_n = adst[n * 8 + hh];
        if (t < 8) denAcc = exSelfS[t];  // include self loop once (slot k==0 lanes)
    }

    float acc = 0.f;
    for (int base = e0; base < e1; base += 8) {
        int rem = e1 - base; if (rem > 8) rem = 8;
        if (t < 64) {
            int k = t >> 3;
            if (k < rem) {
                int e = eid[base + k];
                int s = src[e];
                if (hh == 0) srcS[k] = s;
                float al = asrc[s * 8 + hh] + adst_n + eA[(size_t)e * 8 + hh];
                al = al > 0.f ? al : 0.2f * al;
                float ex = expf(al);
                exS[k][hh] = ex;
                denAcc += ex;
            }
        }
        __syncthreads();
        for (int k = 0; k < rem; ++k)
            acc += exS[k][h] * xs[(size_t)srcS[k] * D + t];
        __syncthreads();
    }
    // self-loop contribution
    acc += exSelfS[h] * xs[(size_t)n * D + t];

    if (t < 64) {  // reduce den over the 8 edge-slots (lane = k*8+hh)
        float d = denAcc;
        d += __shfl_xor(d, 8);
        d += __shfl_xor(d, 16);
        d += __shfl_xor(d, 32);
        if (t < 8) denS[t] = d;
    }
    __syncthreads();

    float outv = acc / (denS[h] + 1e-16f) + bias[t];

    // LayerNorm (unbiased std, eps on sd) + leaky_relu(0.01) + residual
    float s1 = outv, s2 = outv * outv;
    for (int o = 1; o < 64; o <<= 1) { s1 += __shfl_xor(s1, o); s2 += __shfl_xor(s2, o); }
    int w = t >> 6;
    if ((t & 63) == 0) { r1[w] = s1; r2[w] = s2; }
    __syncthreads();
    float tot1 = r1[0] + r1[1] + r1[2] + r1[3];
    float tot2 = r2[0] + r2[1] + r2[2] + r2[3];
    float mu = tot1 / (float)D;
    float var = fmaxf((tot2 - (float)D * mu * mu) / (float)(D - 1), 0.f);
    float sd = sqrtf(var) + 1e-6f;
    float y = gamma[t] * (outv - mu) / sd + beta[t];
    y = y > 0.f ? y : 0.01f * y;
    nf_out[(size_t)n * D + t] = nf_in[(size_t)n * D + t] + y;
}

// ---------------- FFN epilogue: LN + leaky + residual ----------------
__global__ void ln_residual_kernel(const float* __restrict__ hin, const float* __restrict__ nf_in,
                                   const float* __restrict__ gamma, const float* __restrict__ beta,
                                   float* __restrict__ out) {
    int n = blockIdx.x, t = threadIdx.x;
    float v = hin[(size_t)n * D + t];
    float s1 = v, s2 = v * v;
    for (int o = 1; o < 64; o <<= 1) { s1 += __shfl_xor(s1, o); s2 += __shfl_xor(s2, o); }
    __shared__ float r1[4], r2[4];
    int w = t >> 6;
    if ((t & 63) == 0) { r1[w] = s1; r2[w] = s2; }
    __syncthreads();
    float tot1 = r1[0] + r1[1] + r1[2] + r1[3];
    float tot2 = r2[0] + r2[1] + r2[2] + r2[3];
    float mu = tot1 / (float)D;
    float var = fmaxf((tot2 - (float)D * mu * mu) / (float)(D - 1), 0.f);
    float sd = sqrtf(var) + 1e-6f;
    float y = gamma[t] * (v - mu) / sd + beta[t];
    y = y > 0.f ? y : 0.01f * y;
    out[(size_t)n * D + t] = nf_in[(size_t)n * D + t] + y;
}

extern "C" void kernel_launch(void* const* d_in, const int* in_sizes, int n_in,
                              void* d_out, int out_size, void* d_ws, size_t ws_size,
                              hipStream_t stream) {
    const float* nf0    = (const float*)d_in[0];
    const int*   ei     = (const int*)d_in[1];
    const float* ew     = (const float*)d_in[2];
    const float* lin1   = (const float*)d_in[3];
    const float* le1    = (const float*)d_in[4];
    const float* asrc1w = (const float*)d_in[5];
    const float* adst1w = (const float*)d_in[6];
    const float* aedge1 = (const float*)d_in[7];
    const float* b1     = (const float*)d_in[8];
    const float* lin2   = (const float*)d_in[9];
    const float* le2    = (const float*)d_in[10];
    const float* asrc2w = (const float*)d_in[11];
    const float* adst2w = (const float*)d_in[12];
    const float* aedge2 = (const float*)d_in[13];
    const float* b2     = (const float*)d_in[14];
    const float* g1     = (const float*)d_in[15];
    const float* be1    = (const float*)d_in[16];
    const float* g2     = (const float*)d_in[17];
    const float* be2    = (const float*)d_in[18];
    const float* g3     = (const float*)d_in[19];
    const float* be3    = (const float*)d_in[20];
    const float* w1     = (const float*)d_in[21];
    const float* fb1    = (const float*)d_in[22];
    const float* w2     = (const float*)d_in[23];
    const float* fb2    = (const float*)d_in[24];

    const int N = in_sizes[0] / D;
    const int E = in_sizes[1] / 2;
    const int* srcI = ei;
    const int* dstI = ei + E;

    char* ws = (char*)d_ws;
    size_t ob = 0;
    auto alloc = [&](size_t bytes) { void* p = ws + ob; ob = align_up(ob + bytes, 256); return p; };
    int*   deg     = (int*)alloc((size_t)N * 4);
    int*   csr_off = (int*)alloc((size_t)(N + 1) * 4);
    int*   cursor  = (int*)alloc((size_t)N * 4);
    int*   csr_eid = (int*)alloc((size_t)E * 4);
    float* Me1     = (float*)alloc(DE * H * 4);
    float* Me2     = (float*)alloc(DE * H * 4);
    float* sA1     = (float*)alloc((size_t)N * H * 4);
    float* sA2     = (float*)alloc((size_t)N * H * 4);
    float* asrcB   = (float*)alloc((size_t)N * H * 4);
    float* adstB   = (float*)alloc((size_t)N * H * 4);
    float* eA1     = (float*)alloc((size_t)E * H * 4);  // reused as FFN hidden chunk
    float* eA2     = (float*)alloc((size_t)E * H * 4);  // reused as FFN out chunk
    float* xs      = (float*)alloc((size_t)N * D * 4);
    float* nfw     = (float*)alloc((size_t)N * D * 4);
    float* out     = (float*)d_out;

    hipMemsetAsync(deg, 0, (size_t)N * 4, stream);
    hipMemsetAsync(sA1, 0, (size_t)N * H * 4, stream);
    hipMemsetAsync(sA2, 0, (size_t)N * H * 4, stream);

    int eb = (E + 255) / 256;
    deg_kernel<<<eb, 256, 0, stream>>>(dstI, deg, E);
    scan_kernel<<<1, 1024, 0, stream>>>(deg, csr_off, N);
    copy_int_kernel<<<(N + 255) / 256, 256, 0, stream>>>(csr_off, cursor, N);
    fill_kernel<<<eb, 256, 0, stream>>>(dstI, cursor, csr_eid, E);

    me_kernel<<<1, 512, 0, stream>>>(le1, aedge1, Me1);
    me_kernel<<<1, 512, 0, stream>>>(le2, aedge2, Me2);
    ealpha_kernel<<<(int)(((long long)E * H + 255) / 256), 256, 0, stream>>>(
        ew, dstI, Me1, Me2, eA1, eA2, sA1, sA2, E);

    dim3 gx((N + 63) / 64, D / 64);
    // ---- GAT layer 1 ----
    gemm_kernel<<<gx, 256, 0, stream>>>(nf0, lin1, nullptr, xs, N, D, D, 0);
    attnparam_kernel<<<(N * H + 255) / 256, 256, 0, stream>>>(xs, asrc1w, adst1w, asrcB, adstB, N);
    gat_node_kernel<<<N, 256, 0, stream>>>(csr_off, csr_eid, srcI, eA1, sA1, asrcB, adstB,
                                           xs, nf0, b1, g1, be1, nfw);
    // ---- GAT layer 2 ----
    gemm_kernel<<<gx, 256, 0, stream>>>(nfw, lin2, nullptr, xs, N, D, D, 0);
    attnparam_kernel<<<(N * H + 255) / 256, 256, 0, stream>>>(xs, asrc2w, adst2w, asrcB, adstB, N);
    gat_node_kernel<<<N, 256, 0, stream>>>(csr_off, csr_eid, srcI, eA2, sA2, asrcB, adstB,
                                           xs, nfw, b2, g2, be2, nfw);
    // ---- FFN (row chunks so hidden buffer fits in eA scratch) ----
    float* ffh = eA1;  // CH*DF = 2.56M floats == E*H
    float* fft = eA2;
    const int CH = 2500;
    for (int c0 = 0; c0 < N; c0 += CH) {
        int m = (N - c0) < CH ? (N - c0) : CH;
        dim3 gf1((m + 63) / 64, DF / 64);
        gemm_kernel<<<gf1, 256, 0, stream>>>(nfw + (size_t)c0 * D, w1, fb1, ffh, m, DF, D, 1);
        dim3 gf2((m + 63) / 64, D / 64);
        gemm_kernel<<<gf2, 256, 0, stream>>>(ffh, w2, fb2, fft, m, D, DF, 0);
        ln_residual_kernel<<<m, 256, 0, stream>>>(fft, nfw + (size_t)c0 * D, g3, be3,
                                                  out + (size_t)c0 * D);
    }
}

// Round 2
// 469.926 us; speedup vs baseline: 2.2121x; 2.2121x over previous
//
#include <hip/hip_runtime.h>
#include <hip/hip_bf16.h>
#include <math.h>

#define D 256
#define H 8
#define C 32
#define DE 64
#define DF 1024

static inline size_t align_up(size_t x, size_t a) { return (x + a - 1) / a * a; }

typedef __attribute__((ext_vector_type(8))) short short8;
typedef __attribute__((ext_vector_type(4))) float f32x4;

__device__ inline unsigned short f2b(float x) {
    __hip_bfloat16 h = __float2bfloat16(x);
    return *reinterpret_cast<unsigned short*>(&h);
}

// ---------------- CSR build ----------------
__global__ void deg_kernel(const int* __restrict__ dst, int* __restrict__ deg, int E) {
    int e = blockIdx.x * 256 + threadIdx.x;
    if (e < E) atomicAdd(&deg[dst[e]], 1);
}

__global__ void scan_kernel(const int* __restrict__ deg, int* __restrict__ off, int n) {
    __shared__ int buf[1024];
    __shared__ int carryS;
    int tid = threadIdx.x;
    if (tid == 0) carryS = 0;
    __syncthreads();
    for (int base = 0; base < n; base += 1024) {
        int i = base + tid;
        int v = (i < n) ? deg[i] : 0;
        buf[tid] = v;
        __syncthreads();
        for (int s = 1; s < 1024; s <<= 1) {
            int tmp = (tid >= s) ? buf[tid - s] : 0;
            __syncthreads();
            if (tid >= s) buf[tid] += tmp;
            __syncthreads();
        }
        if (i < n) off[i] = carryS + buf[tid] - v;  // exclusive
        __syncthreads();
        if (tid == 0) carryS += buf[1023];
        __syncthreads();
    }
    if (tid == 0) off[n] = carryS;
}

__global__ void copy_int_kernel(const int* __restrict__ a, int* __restrict__ b, int n) {
    int i = blockIdx.x * 256 + threadIdx.x;
    if (i < n) b[i] = a[i];
}

__global__ void fill_kernel(const int* __restrict__ dst, int* __restrict__ cursor,
                            int* __restrict__ eid, int E) {
    int e = blockIdx.x * 256 + threadIdx.x;
    if (e < E) {
        int p = atomicAdd(&cursor[dst[e]], 1);
        eid[p] = e;
    }
}

// ---------------- bf16 conversion / transpose ----------------
__global__ void convert_bf16_kernel(const float* __restrict__ in, unsigned short* __restrict__ out,
                                    size_t n_valid, size_t n_total) {
    size_t i = (size_t)blockIdx.x * 256 + threadIdx.x;
    if (i < n_total) out[i] = (i < n_valid) ? f2b(in[i]) : (unsigned short)0;
}

// in: [K][N] fp32  ->  out: [N][K] bf16
__global__ void transpose_bf16_kernel(const float* __restrict__ in, unsigned short* __restrict__ out,
                                      int K, int N) {
    __shared__ float tile[32][33];
    int bn = blockIdx.x * 32, bk = blockIdx.y * 32;
    int tx = threadIdx.x & 31, ty = threadIdx.x >> 5;  // 256 thr: ty 0..7
    for (int i = ty; i < 32; i += 8) {
        int k = bk + i, n = bn + tx;
        tile[i][tx] = (k < K && n < N) ? in[(size_t)k * N + n] : 0.f;
    }
    __syncthreads();
    for (int i = ty; i < 32; i += 8) {
        int n = bn + i, k = bk + tx;
        if (n < N && k < K) out[(size_t)n * K + k] = f2b(tile[tx][i]);
    }
}

// ---------------- bf16 MFMA GEMM: C = A[MxK] @ BT[NxK]^T (+bias)(+relu) ----------------
// 128x128 tile, BK=64, 4 waves (2x2 of 64x64), mfma_f32_16x16x32_bf16, fp32 acc.
__global__ __launch_bounds__(256) void mfma_gemm_kernel(
    const unsigned short* __restrict__ A, const unsigned short* __restrict__ BT,
    const float* __restrict__ bias, float* __restrict__ Cf, unsigned short* __restrict__ Cb,
    int M, int Nc, int K, int relu) {
    __shared__ unsigned short As[128 * 64];
    __shared__ unsigned short Bs[128 * 64];
    int t = threadIdx.x;
    int lane = t & 63, w = t >> 6;
    int gm0 = blockIdx.x * 128, gn0 = blockIdx.y * 128;
    f32x4 acc[4][4] = {};
    int srow = lane >> 3, scol = (lane & 7) * 8;  // staging: 8 rows x 64 cols per wave-load
    int wm = (w >> 1) * 64, wn = (w & 1) * 64;
    int fr = lane & 15, fk = (lane >> 4) * 8;

    for (int k0 = 0; k0 < K; k0 += 64) {
        __syncthreads();
#pragma unroll
        for (int i = 0; i < 4; ++i) {
            int rb = w * 32 + i * 8;
            const unsigned short* ga = A + (size_t)(gm0 + rb + srow) * K + k0 + scol;
            __builtin_amdgcn_global_load_lds(
                (const __attribute__((address_space(1))) unsigned int*)ga,
                (__attribute__((address_space(3))) unsigned int*)&As[rb * 64], 16, 0, 0);
            const unsigned short* gb = BT + (size_t)(gn0 + rb + srow) * K + k0 + scol;
            __builtin_amdgcn_global_load_lds(
                (const __attribute__((address_space(1))) unsigned int*)gb,
                (__attribute__((address_space(3))) unsigned int*)&Bs[rb * 64], 16, 0, 0);
        }
        __syncthreads();
#pragma unroll
        for (int kk = 0; kk < 64; kk += 32) {
            short8 a[4], b[4];
#pragma unroll
            for (int m = 0; m < 4; ++m)
                a[m] = *(const short8*)&As[(wm + m * 16 + fr) * 64 + kk + fk];
#pragma unroll
            for (int n = 0; n < 4; ++n)
                b[n] = *(const short8*)&Bs[(wn + n * 16 + fr) * 64 + kk + fk];
#pragma unroll
            for (int m = 0; m < 4; ++m)
#pragma unroll
                for (int n = 0; n < 4; ++n)
                    acc[m][n] = __builtin_amdgcn_mfma_f32_16x16x32_bf16(a[m], b[n], acc[m][n], 0, 0, 0);
        }
    }
    int fcol = lane & 15, frow4 = (lane >> 4) * 4;
#pragma unroll
    for (int m = 0; m < 4; ++m) {
#pragma unroll
        for (int i = 0; i < 4; ++i) {
            int gr = gm0 + wm + m * 16 + frow4 + i;
            if (gr >= M) continue;
#pragma unroll
            for (int n = 0; n < 4; ++n) {
                int gc = gn0 + wn + n * 16 + fcol;
                float v = acc[m][n][i];
                if (bias) v += bias[gc];
                if (relu) v = fmaxf(v, 0.f);
                if (Cb) Cb[(size_t)gr * Nc + gc] = f2b(v);
                else    Cf[(size_t)gr * Nc + gc] = v;
            }
        }
    }
}

// ---------------- edge-attention projection ----------------
// Me[d,h] = sum_c We[d, h*C+c] * ae[h,c]
__global__ void me_kernel(const float* __restrict__ We, const float* __restrict__ ae,
                          float* __restrict__ Me) {
    int t = threadIdx.x;  // 512 threads
    int d = t >> 3, h = t & 7;
    float s = 0.f;
    for (int c = 0; c < C; ++c) s += We[d * (H * C) + h * C + c] * ae[h * C + c];
    Me[d * H + h] = s;
}

__global__ void ealpha_kernel(const float* __restrict__ ew, const int* __restrict__ dst,
                              const float* __restrict__ Me1, const float* __restrict__ Me2,
                              float* __restrict__ eA1, float* __restrict__ eA2,
                              float* __restrict__ sA1, float* __restrict__ sA2, int E) {
    __shared__ float M1[DE * H], M2[DE * H];
    int t = threadIdx.x;
    for (int i = t; i < DE * H; i += 256) { M1[i] = Me1[i]; M2[i] = Me2[i]; }
    __syncthreads();
    long long idx = (long long)blockIdx.x * 256 + t;
    int e = (int)(idx >> 3), hh = (int)(idx & 7);
    if (e < E) {
        const float* row = ew + (size_t)e * DE;
        float a1 = 0.f, a2 = 0.f;
        for (int d = 0; d < DE; ++d) {
            float v = row[d];
            a1 += v * M1[d * H + hh];
            a2 += v * M2[d * H + hh];
        }
        eA1[(size_t)e * H + hh] = a1;
        eA2[(size_t)e * H + hh] = a2;
        int dn = dst[e];
        atomicAdd(&sA1[dn * H + hh], a1);
        atomicAdd(&sA2[dn * H + hh], a2);
    }
}

__global__ void attnparam_kernel(const float* __restrict__ xs, const float* __restrict__ a_s,
                                 const float* __restrict__ a_d, float* __restrict__ asrc,
                                 float* __restrict__ adst, int N) {
    __shared__ float AS[D], AD[D];
    int t = threadIdx.x;
    AS[t] = a_s[t]; AD[t] = a_d[t];
    __syncthreads();
    int idx = blockIdx.x * 256 + t;
    int n = idx >> 3, hh = idx & 7;
    if (n < N) {
        const float* row = xs + (size_t)n * D + hh * C;
        float s1 = 0.f, s2 = 0.f;
        for (int c = 0; c < C; ++c) {
            float v = row[c];
            s1 += v * AS[hh * C + c];
            s2 += v * AD[hh * C + c];
        }
        asrc[idx] = s1; adst[idx] = s2;
    }
}

// ---------------- GAT per-node aggregation + fused LN/leaky/residual ----------------
__global__ __launch_bounds__(256) void gat_node_kernel(
    const int* __restrict__ off, const int* __restrict__ eid, const int* __restrict__ src,
    const float* __restrict__ eA, const float* __restrict__ sA,
    const float* __restrict__ asrc, const float* __restrict__ adst,
    const float* __restrict__ xs, const float* __restrict__ nf_in,
    const float* __restrict__ bias, const float* __restrict__ gamma,
    const float* __restrict__ beta, float* __restrict__ nf_out) {
    int n = blockIdx.x;
    int t = threadIdx.x;
    int h = t >> 5;
    __shared__ float exS[8][8];
    __shared__ int srcS[8];
    __shared__ float exSelfS[8];
    __shared__ float denS[8];
    __shared__ float r1[4], r2[4];

    int e0 = off[n], e1 = off[n + 1];
    int degn = e1 - e0;

    if (t < 8) {
        float sa = sA[n * 8 + t] / (float)(degn > 0 ? degn : 1);
        float al = asrc[n * 8 + t] + adst[n * 8 + t] + sa;
        al = al > 0.f ? al : 0.2f * al;
        exSelfS[t] = expf(al);
    }
    __syncthreads();

    int hh = t & 7;
    float adst_n = 0.f, denAcc = 0.f;
    if (t < 64) {
        adst_n = adst[n * 8 + hh];
        if (t < 8) denAcc = exSelfS[t];
    }

    float acc = 0.f;
    for (int base = e0; base < e1; base += 8) {
        int rem = e1 - base; if (rem > 8) rem = 8;
        if (t < 64) {
            int k = t >> 3;
            if (k < rem) {
                int e = eid[base + k];
                int s = src[e];
                if (hh == 0) srcS[k] = s;
                float al = asrc[s * 8 + hh] + adst_n + eA[(size_t)e * 8 + hh];
                al = al > 0.f ? al : 0.2f * al;
                float ex = expf(al);
                exS[k][hh] = ex;
                denAcc += ex;
            }
        }
        __syncthreads();
        for (int k = 0; k < rem; ++k)
            acc += exS[k][h] * xs[(size_t)srcS[k] * D + t];
        __syncthreads();
    }
    acc += exSelfS[h] * xs[(size_t)n * D + t];

    if (t < 64) {
        float d = denAcc;
        d += __shfl_xor(d, 8);
        d += __shfl_xor(d, 16);
        d += __shfl_xor(d, 32);
        if (t < 8) denS[t] = d;
    }
    __syncthreads();

    float outv = acc / (denS[h] + 1e-16f) + bias[t];

    float s1 = outv, s2 = outv * outv;
    for (int o = 1; o < 64; o <<= 1) { s1 += __shfl_xor(s1, o); s2 += __shfl_xor(s2, o); }
    int w = t >> 6;
    if ((t & 63) == 0) { r1[w] = s1; r2[w] = s2; }
    __syncthreads();
    float tot1 = r1[0] + r1[1] + r1[2] + r1[3];
    float tot2 = r2[0] + r2[1] + r2[2] + r2[3];
    float mu = tot1 / (float)D;
    float var = fmaxf((tot2 - (float)D * mu * mu) / (float)(D - 1), 0.f);
    float sd = sqrtf(var) + 1e-6f;
    float y = gamma[t] * (outv - mu) / sd + beta[t];
    y = y > 0.f ? y : 0.01f * y;
    nf_out[(size_t)n * D + t] = nf_in[(size_t)n * D + t] + y;
}

// ---------------- FFN epilogue: LN + leaky + residual ----------------
__global__ void ln_residual_kernel(const float* __restrict__ hin, const float* __restrict__ nf_in,
                                   const float* __restrict__ gamma, const float* __restrict__ beta,
                                   float* __restrict__ out) {
    int n = blockIdx.x, t = threadIdx.x;
    float v = hin[(size_t)n * D + t];
    float s1 = v, s2 = v * v;
    for (int o = 1; o < 64; o <<= 1) { s1 += __shfl_xor(s1, o); s2 += __shfl_xor(s2, o); }
    __shared__ float r1[4], r2[4];
    int w = t >> 6;
    if ((t & 63) == 0) { r1[w] = s1; r2[w] = s2; }
    __syncthreads();
    float tot1 = r1[0] + r1[1] + r1[2] + r1[3];
    float tot2 = r2[0] + r2[1] + r2[2] + r2[3];
    float mu = tot1 / (float)D;
    float var = fmaxf((tot2 - (float)D * mu * mu) / (float)(D - 1), 0.f);
    float sd = sqrtf(var) + 1e-6f;
    float y = gamma[t] * (v - mu) / sd + beta[t];
    y = y > 0.f ? y : 0.01f * y;
    out[(size_t)n * D + t] = nf_in[(size_t)n * D + t] + y;
}

extern "C" void kernel_launch(void* const* d_in, const int* in_sizes, int n_in,
                              void* d_out, int out_size, void* d_ws, size_t ws_size,
                              hipStream_t stream) {
    const float* nf0    = (const float*)d_in[0];
    const int*   ei     = (const int*)d_in[1];
    const float* ew     = (const float*)d_in[2];
    const float* lin1   = (const float*)d_in[3];
    const float* le1    = (const float*)d_in[4];
    const float* asrc1w = (const float*)d_in[5];
    const float* adst1w = (const float*)d_in[6];
    const float* aedge1 = (const float*)d_in[7];
    const float* b1     = (const float*)d_in[8];
    const float* lin2   = (const float*)d_in[9];
    const float* le2    = (const float*)d_in[10];
    const float* asrc2w = (const float*)d_in[11];
    const float* adst2w = (const float*)d_in[12];
    const float* aedge2 = (const float*)d_in[13];
    const float* b2     = (const float*)d_in[14];
    const float* g1     = (const float*)d_in[15];
    const float* be1    = (const float*)d_in[16];
    const float* g2     = (const float*)d_in[17];
    const float* be2    = (const float*)d_in[18];
    const float* g3     = (const float*)d_in[19];
    const float* be3    = (const float*)d_in[20];
    const float* w1     = (const float*)d_in[21];
    const float* fb1    = (const float*)d_in[22];
    const float* w2     = (const float*)d_in[23];
    const float* fb2    = (const float*)d_in[24];

    const int N = in_sizes[0] / D;
    const int E = in_sizes[1] / 2;
    const int Mpad = ((N + 127) / 128) * 128;
    const int* srcI = ei;
    const int* dstI = ei + E;

    char* ws = (char*)d_ws;
    size_t ob = 0;
    auto alloc = [&](size_t bytes) { void* p = ws + ob; ob = align_up(ob + bytes, 256); return p; };
    // --- arena0: dead after GAT layer 2; reused as FFN hidden (bf16, Mpad*DF*2 = 20.7MB) ---
    int*   deg     = (int*)alloc((size_t)N * 4);
    int*   csr_off = (int*)alloc((size_t)(N + 1) * 4);
    int*   cursor  = (int*)alloc((size_t)N * 4);
    int*   csr_eid = (int*)alloc((size_t)E * 4);
    float* Me1     = (float*)alloc(DE * H * 4);
    float* Me2     = (float*)alloc(DE * H * 4);
    float* sA1     = (float*)alloc((size_t)N * H * 4);
    float* sA2     = (float*)alloc((size_t)N * H * 4);
    float* asrcB   = (float*)alloc((size_t)N * H * 4);
    float* adstB   = (float*)alloc((size_t)N * H * 4);
    float* eA1     = (float*)alloc((size_t)E * H * 4);
    float* eA2     = (float*)alloc((size_t)E * H * 4);
    size_t arena0_end = ob;  // ~23.1MB — covers hidden (20.7MB)
    float* xsf     = (float*)alloc((size_t)Mpad * D * 4);  // xs; later FFN out (fft)
    // --- persistent across FFN ---
    float* nfw     = (float*)alloc((size_t)N * D * 4);
    unsigned short* Abf   = (unsigned short*)alloc((size_t)Mpad * D * 2);
    unsigned short* lin1T = (unsigned short*)alloc((size_t)D * D * 2);
    unsigned short* lin2T = (unsigned short*)alloc((size_t)D * D * 2);
    unsigned short* w1T   = (unsigned short*)alloc((size_t)DF * D * 2);
    unsigned short* w2T   = (unsigned short*)alloc((size_t)D * DF * 2);
    unsigned short* hidden = (unsigned short*)ws;  // aliases arena0
    (void)arena0_end; (void)ws_size;
    float* out = (float*)d_out;

    hipMemsetAsync(deg, 0, (size_t)N * 4, stream);
    hipMemsetAsync(sA1, 0, (size_t)N * H * 4, stream);
    hipMemsetAsync(sA2, 0, (size_t)N * H * 4, stream);

    int eb = (E + 255) / 256;
    deg_kernel<<<eb, 256, 0, stream>>>(dstI, deg, E);
    scan_kernel<<<1, 1024, 0, stream>>>(deg, csr_off, N);
    copy_int_kernel<<<(N + 255) / 256, 256, 0, stream>>>(csr_off, cursor, N);
    fill_kernel<<<eb, 256, 0, stream>>>(dstI, cursor, csr_eid, E);

    me_kernel<<<1, 512, 0, stream>>>(le1, aedge1, Me1);
    me_kernel<<<1, 512, 0, stream>>>(le2, aedge2, Me2);
    ealpha_kernel<<<(int)(((long long)E * H + 255) / 256), 256, 0, stream>>>(
        ew, dstI, Me1, Me2, eA1, eA2, sA1, sA2, E);

    // weight transposes -> bf16 [N][K]
    transpose_bf16_kernel<<<dim3(D / 32, D / 32), 256, 0, stream>>>(lin1, lin1T, D, D);
    transpose_bf16_kernel<<<dim3(D / 32, D / 32), 256, 0, stream>>>(lin2, lin2T, D, D);
    transpose_bf16_kernel<<<dim3(DF / 32, D / 32), 256, 0, stream>>>(w1, w1T, D, DF);
    transpose_bf16_kernel<<<dim3(D / 32, DF / 32), 256, 0, stream>>>(w2, w2T, DF, D);

    const size_t nvalid = (size_t)N * D, ntot = (size_t)Mpad * D;
    int cb = (int)(ntot / 256);

    // ---- GAT layer 1 ----
    convert_bf16_kernel<<<cb, 256, 0, stream>>>(nf0, Abf, nvalid, ntot);
    mfma_gemm_kernel<<<dim3(Mpad / 128, D / 128), 256, 0, stream>>>(
        Abf, lin1T, nullptr, xsf, nullptr, N, D, D, 0);
    attnparam_kernel<<<(N * H + 255) / 256, 256, 0, stream>>>(xsf, asrc1w, adst1w, asrcB, adstB, N);
    gat_node_kernel<<<N, 256, 0, stream>>>(csr_off, csr_eid, srcI, eA1, sA1, asrcB, adstB,
                                           xsf, nf0, b1, g1, be1, nfw);
    // ---- GAT layer 2 ----
    convert_bf16_kernel<<<cb, 256, 0, stream>>>(nfw, Abf, nvalid, ntot);
    mfma_gemm_kernel<<<dim3(Mpad / 128, D / 128), 256, 0, stream>>>(
        Abf, lin2T, nullptr, xsf, nullptr, N, D, D, 0);
    attnparam_kernel<<<(N * H + 255) / 256, 256, 0, stream>>>(xsf, asrc2w, adst2w, asrcB, adstB, N);
    gat_node_kernel<<<N, 256, 0, stream>>>(csr_off, csr_eid, srcI, eA2, sA2, asrcB, adstB,
                                           xsf, nfw, b2, g2, be2, nfw);
    // ---- FFN: hidden = relu(nfw@w1+fb1) in bf16; fft = hidden@w2+fb2 in fp32 ----
    convert_bf16_kernel<<<cb, 256, 0, stream>>>(nfw, Abf, nvalid, ntot);
    mfma_gemm_kernel<<<dim3(Mpad / 128, DF / 128), 256, 0, stream>>>(
        Abf, w1T, fb1, nullptr, hidden, N, DF, D, 1);
    mfma_gemm_kernel<<<dim3(Mpad / 128, D / 128), 256, 0, stream>>>(
        hidden, w2T, fb2, xsf, nullptr, N, D, DF, 0);
    ln_residual_kernel<<<N, 256, 0, stream>>>(xsf, nfw, g3, be3, out);
}